// Round 2
// baseline (772.086 us; speedup 1.0000x reference)
//
#include <hip/hip_runtime.h>
#include <hip/hip_bf16.h>

#define NN 50000
#define NE 800000

typedef __bf16 bf16_t;
typedef bf16_t bf16x8 __attribute__((ext_vector_type(8)));
typedef float f32x4 __attribute__((ext_vector_type(4)));

__device__ __forceinline__ float gelu_f(float x) {
    return 0.5f * x * (1.0f + erff(x * 0.70710678118654752440f));
}

// ---------------- weight folding: bn(x)@W = x@(diag(s)W) + (b-mu*s)@W ----------------
// fp32 inputs -> bf16 transposed weights Wt[n][k] + fp32 folded bias
__device__ void fold_layer(int K, const float* W, const float* g, const float* b,
                           const float* mu, const float* v, const float* c,
                           bf16_t* Wt, float* cb, int n) {
    float acc = c[n];
    for (int k = 0; k < K; ++k) {
        float w = W[k * 64 + n];
        float s = 1.0f, o = 0.0f;
        if (g) {
            s = g[k] / sqrtf(v[k] + 1e-3f);
            o = b[k] - mu[k] * s;
        }
        Wt[n * K + k] = (bf16_t)(w * s);   // transposed: Wt[n][k]
        acc += o * w;
    }
    cb[n] = acc;
}

__global__ void fold_kernel(
    const float* mg1, const float* mb1, const float* mmu1, const float* mv1,
    const float* mW1, const float* mc1,
    const float* mg2, const float* mb2, const float* mmu2, const float* mv2,
    const float* mW2, const float* mc2,
    const float* eW1, const float* ec1, const float* eW2, const float* ec2,
    const float* ug1, const float* ub1, const float* umu1, const float* uv1,
    const float* uW1, const float* uc1,
    const float* ug2, const float* ub2, const float* umu2, const float* uv2,
    const float* uW2, const float* uc2,
    bf16_t* mW1t, float* cm1, bf16_t* mW2t, float* cm2,
    bf16_t* eW1t, float* ce1, bf16_t* eW2t, float* ce2,
    bf16_t* uW1t, float* cu1, bf16_t* uW2t, float* cu2)
{
    int n = threadIdx.x;
    if (n >= 64) return;
    fold_layer(64,  mW1, mg1, mb1, mmu1, mv1, mc1, mW1t, cm1, n);
    fold_layer(64,  mW2, mg2, mb2, mmu2, mv2, mc2, mW2t, cm2, n);
    fold_layer(64,  eW1, nullptr, nullptr, nullptr, nullptr, ec1, eW1t, ce1, n);
    fold_layer(64,  eW2, nullptr, nullptr, nullptr, nullptr, ec2, eW2t, ce2, n);
    fold_layer(128, uW1, ug1, ub1, umu1, uv1, uc1, uW1t, cu1, n);
    fold_layer(64,  uW2, ug2, ub2, umu2, uv2, uc2, uW2t, cu2, n);
}

// ---------------- helpers ----------------
// fp32 row (64 floats) -> hi/lo bf16 fragments for k=0..31 (hi0/lo0) and k=32..63 (hi1/lo1)
__device__ __forceinline__ void mk_frag_hilo(const float* row, int quad,
        bf16x8& hi0, bf16x8& lo0, bf16x8& hi1, bf16x8& lo1)
{
    #pragma unroll
    for (int j = 0; j < 8; ++j) {
        float x0 = row[quad * 8 + j];
        float x1 = row[32 + quad * 8 + j];
        bf16_t h0 = (bf16_t)x0, h1 = (bf16_t)x1;
        hi0[j] = h0; lo0[j] = (bf16_t)(x0 - (float)h0);
        hi1[j] = h1; lo1[j] = (bf16_t)(x1 - (float)h1);
    }
}

__device__ __forceinline__ void gemm64_hilo(bf16x8 h0, bf16x8 l0, bf16x8 h1, bf16x8 l1,
        const bf16_t (*w)[72], f32x4 (&acc)[4], int lrow, int quad)
{
    #pragma unroll
    for (int nt = 0; nt < 4; ++nt) {
        const bf16_t* wr = w[nt * 16 + lrow];
        bf16x8 b0 = *(const bf16x8*)(wr + quad * 8);
        bf16x8 b1 = *(const bf16x8*)(wr + 32 + quad * 8);
        f32x4 c = {0.f, 0.f, 0.f, 0.f};
        c = __builtin_amdgcn_mfma_f32_16x16x32_bf16(h0, b0, c, 0, 0, 0);
        c = __builtin_amdgcn_mfma_f32_16x16x32_bf16(l0, b0, c, 0, 0, 0);
        c = __builtin_amdgcn_mfma_f32_16x16x32_bf16(h1, b1, c, 0, 0, 0);
        c = __builtin_amdgcn_mfma_f32_16x16x32_bf16(l1, b1, c, 0, 0, 0);
        acc[nt] = c;
    }
}

__device__ __forceinline__ void gemm64_lds(const bf16x8 a0, const bf16x8 a1,
        const bf16_t (*w)[72], f32x4 (&acc)[4], int lrow, int quad)
{
    #pragma unroll
    for (int nt = 0; nt < 4; ++nt) {
        const bf16_t* wr = w[nt * 16 + lrow];
        bf16x8 b0 = *(const bf16x8*)(wr + quad * 8);
        bf16x8 b1 = *(const bf16x8*)(wr + 32 + quad * 8);
        f32x4 c = {0.f, 0.f, 0.f, 0.f};
        c = __builtin_amdgcn_mfma_f32_16x16x32_bf16(a0, b0, c, 0, 0, 0);
        c = __builtin_amdgcn_mfma_f32_16x16x32_bf16(a1, b1, c, 0, 0, 0);
        acc[nt] = c;
    }
}

__device__ __forceinline__ void epi_to_lds(const f32x4 (&acc)[4], const float* bias,
        bf16_t (*h)[72], int lrow, int quad)
{
    #pragma unroll
    for (int nt = 0; nt < 4; ++nt) {
        int col = nt * 16 + lrow;
        float bb = bias[col];
        #pragma unroll
        for (int r = 0; r < 4; ++r)
            h[quad * 4 + r][col] = (bf16_t)gelu_f(acc[nt][r] + bb);
    }
}

// ---------------- edge kernel: msg/er MLPs + gated scatter ----------------
__global__ __launch_bounds__(256) void edge_kernel(
    const float* __restrict__ node_feats, const float* __restrict__ edge_feats,
    const int* __restrict__ src, const int* __restrict__ dst,
    const bf16_t* __restrict__ mW1t, const float* __restrict__ cm1,
    const bf16_t* __restrict__ mW2t, const float* __restrict__ cm2,
    const bf16_t* __restrict__ eW1t, const float* __restrict__ ce1,
    const bf16_t* __restrict__ eW2t, const float* __restrict__ ce2,
    float* __restrict__ s_acc, int* __restrict__ cnt)
{
    __shared__ bf16_t w_lds[4][64][72];   // mW1t, mW2t, eW1t, eW2t; +8 pad -> 2-way banks (free)
    __shared__ bf16_t h_lds[4][16][72];   // per-wave layer1->layer2 round-trip

    const int tid  = threadIdx.x;
    const int wave = tid >> 6;
    const int lane = tid & 63;
    const int quad = lane >> 4;
    const int lrow = lane & 15;

    #pragma unroll
    for (int m = 0; m < 4; ++m) {
        const bf16_t* Wp = (m == 0) ? mW1t : (m == 1) ? mW2t : (m == 2) ? eW1t : eW2t;
        #pragma unroll
        for (int j = 0; j < 2; ++j) {
            int chunk = tid + j * 256;        // 0..511
            int row = chunk >> 3;
            int c8  = chunk & 7;
            *(bf16x8*)(&w_lds[m][row][c8 * 8]) = *(const bf16x8*)(Wp + row * 64 + c8 * 8);
        }
    }
    __syncthreads();

    const int ebase = blockIdx.x * 64 + wave * 16;

    // per-edge count (exactly once: lanes 0..15 of each wave)
    if (quad == 0) atomicAdd(&cnt[src[ebase + lrow]], 1);

    f32x4 acc[4];

    // ---- edge-transformer path: er = gelu(gelu(ef@eW1+c1)@eW2+c2) ----
    {
        const float* erow = edge_feats + (size_t)(ebase + lrow) * 64;
        bf16x8 h0, l0, h1, l1;
        mk_frag_hilo(erow, quad, h0, l0, h1, l1);
        gemm64_hilo(h0, l0, h1, l1, w_lds[2], acc, lrow, quad);
        epi_to_lds(acc, ce1, h_lds[wave], lrow, quad);
    }
    __syncthreads();
    float er[4][4];
    {
        bf16x8 a0 = *(const bf16x8*)(&h_lds[wave][lrow][quad * 8]);
        bf16x8 a1 = *(const bf16x8*)(&h_lds[wave][lrow][32 + quad * 8]);
        gemm64_lds(a0, a1, w_lds[3], acc, lrow, quad);
        #pragma unroll
        for (int nt = 0; nt < 4; ++nt) {
            float bb = ce2[nt * 16 + lrow];
            #pragma unroll
            for (int r = 0; r < 4; ++r) er[nt][r] = gelu_f(acc[nt][r] + bb);
        }
    }
    __syncthreads();

    // ---- message path: msg = gelu(bn-folded(nbr)@mW1' ... ) ----
    {
        const int dnode = dst[ebase + lrow];
        const float* nrow = node_feats + (size_t)dnode * 64;
        bf16x8 h0, l0, h1, l1;
        mk_frag_hilo(nrow, quad, h0, l0, h1, l1);
        gemm64_hilo(h0, l0, h1, l1, w_lds[0], acc, lrow, quad);
        epi_to_lds(acc, cm1, h_lds[wave], lrow, quad);
    }
    __syncthreads();
    float msg[4][4];
    {
        bf16x8 a0 = *(const bf16x8*)(&h_lds[wave][lrow][quad * 8]);
        bf16x8 a1 = *(const bf16x8*)(&h_lds[wave][lrow][32 + quad * 8]);
        gemm64_lds(a0, a1, w_lds[1], acc, lrow, quad);
        #pragma unroll
        for (int nt = 0; nt < 4; ++nt) {
            float bb = cm2[nt * 16 + lrow];
            #pragma unroll
            for (int r = 0; r < 4; ++r) msg[nt][r] = gelu_f(acc[nt][r] + bb);
        }
    }

    // ---- gate + scatter (C layout: row = quad*4+r, col = nt*16+lrow) ----
    int se[4];
    #pragma unroll
    for (int r = 0; r < 4; ++r) se[r] = src[ebase + quad * 4 + r];
    #pragma unroll
    for (int nt = 0; nt < 4; ++nt) {
        int col = nt * 16 + lrow;
        #pragma unroll
        for (int r = 0; r < 4; ++r) {
            float v = msg[nt][r] * er[nt][r];
            unsafeAtomicAdd(&s_acc[(size_t)se[r] * 64 + col], v);
        }
    }
}

// ---------------- node kernel: concat + update MLP ----------------
__global__ __launch_bounds__(256) void node_kernel(
    const float* __restrict__ node_feats,
    const float* __restrict__ s_acc, const int* __restrict__ cnt,
    const bf16_t* __restrict__ uW1t, const float* __restrict__ cu1,
    const bf16_t* __restrict__ uW2t, const float* __restrict__ cu2,
    float* __restrict__ out)
{
    __shared__ bf16_t w1_lds[64][136];   // [n][k], K=128, +8 pad
    __shared__ bf16_t w2_lds[64][72];
    __shared__ bf16_t h_lds[4][16][72];

    const int tid  = threadIdx.x;
    const int wave = tid >> 6;
    const int lane = tid & 63;
    const int quad = lane >> 4;
    const int lrow = lane & 15;

    #pragma unroll
    for (int i = 0; i < 4; ++i) {
        int chunk = tid + i * 256;        // 0..1023
        int row = chunk >> 4;
        int c8  = chunk & 15;
        *(bf16x8*)(&w1_lds[row][c8 * 8]) = *(const bf16x8*)(uW1t + row * 128 + c8 * 8);
    }
    #pragma unroll
    for (int i = 0; i < 2; ++i) {
        int chunk = tid + i * 256;        // 0..511
        int row = chunk >> 3;
        int c8  = chunk & 7;
        *(bf16x8*)(&w2_lds[row][c8 * 8]) = *(const bf16x8*)(uW2t + row * 64 + c8 * 8);
    }
    __syncthreads();

    const int nbase  = blockIdx.x * 64 + wave * 16;
    int arow = nbase + lrow;
    arow = arow < NN ? arow : NN - 1;     // clamp gather; stores predicated below

    // build hcat = [node_feats | s_acc/cnt] hi/lo fragments (K=128)
    const float* nf = node_feats + (size_t)arow * 64;
    float inv = 1.0f / fmaxf((float)cnt[arow], 1.0f);
    const float* srow = s_acc + (size_t)arow * 64;

    bf16x8 ah[4], al[4];
    #pragma unroll
    for (int j = 0; j < 8; ++j) {
        float x0 = nf[quad * 8 + j];
        float x1 = nf[32 + quad * 8 + j];
        float x2 = srow[quad * 8 + j] * inv;
        float x3 = srow[32 + quad * 8 + j] * inv;
        bf16_t h0 = (bf16_t)x0, h1 = (bf16_t)x1, h2 = (bf16_t)x2, h3 = (bf16_t)x3;
        ah[0][j] = h0; al[0][j] = (bf16_t)(x0 - (float)h0);
        ah[1][j] = h1; al[1][j] = (bf16_t)(x1 - (float)h1);
        ah[2][j] = h2; al[2][j] = (bf16_t)(x2 - (float)h2);
        ah[3][j] = h3; al[3][j] = (bf16_t)(x3 - (float)h3);
    }

    f32x4 acc[4];
    #pragma unroll
    for (int nt = 0; nt < 4; ++nt) {
        const bf16_t* wr = w1_lds[nt * 16 + lrow];
        f32x4 c = {0.f, 0.f, 0.f, 0.f};
        #pragma unroll
        for (int kk = 0; kk < 4; ++kk) {
            bf16x8 b = *(const bf16x8*)(wr + kk * 32 + quad * 8);
            c = __builtin_amdgcn_mfma_f32_16x16x32_bf16(ah[kk], b, c, 0, 0, 0);
            c = __builtin_amdgcn_mfma_f32_16x16x32_bf16(al[kk], b, c, 0, 0, 0);
        }
        acc[nt] = c;
    }
    epi_to_lds(acc, cu1, h_lds[wave], lrow, quad);
    __syncthreads();

    bf16x8 ha0 = *(const bf16x8*)(&h_lds[wave][lrow][quad * 8]);
    bf16x8 ha1 = *(const bf16x8*)(&h_lds[wave][lrow][32 + quad * 8]);
    gemm64_lds(ha0, ha1, w2_lds, acc, lrow, quad);

    #pragma unroll
    for (int nt = 0; nt < 4; ++nt) {
        int col = nt * 16 + lrow;
        float bb = cu2[col];
        #pragma unroll
        for (int r = 0; r < 4; ++r) {
            int row = nbase + quad * 4 + r;
            if (row < NN)
                out[(size_t)row * 64 + col] = gelu_f(acc[nt][r] + bb);
        }
    }
}

// ---------------- launch ----------------
extern "C" void kernel_launch(void* const* d_in, const int* in_sizes, int n_in,
                              void* d_out, int out_size, void* d_ws, size_t ws_size,
                              hipStream_t stream) {
    const float* node_feats = (const float*)d_in[0];
    const float* edge_feats = (const float*)d_in[1];
    const int*   src        = (const int*)d_in[2];
    const int*   dst        = (const int*)d_in[3];

    char* ws = (char*)d_ws;
    const size_t S_BYTES = (size_t)NN * 64 * 4;       // 12,800,000
    const size_t C_BYTES = (size_t)NN * 4;            //    200,000
    float* s_acc = (float*)ws;
    int*   cnt   = (int*)(ws + S_BYTES);
    size_t off = S_BYTES + C_BYTES;                   // 13,000,000 (16-aligned)
    bf16_t* mW1t = (bf16_t*)(ws + off); off += 8192;
    bf16_t* mW2t = (bf16_t*)(ws + off); off += 8192;
    bf16_t* eW1t = (bf16_t*)(ws + off); off += 8192;
    bf16_t* eW2t = (bf16_t*)(ws + off); off += 8192;
    bf16_t* uW1t = (bf16_t*)(ws + off); off += 16384;
    bf16_t* uW2t = (bf16_t*)(ws + off); off += 8192;
    float* cm1 = (float*)(ws + off); off += 256;
    float* cm2 = (float*)(ws + off); off += 256;
    float* ce1 = (float*)(ws + off); off += 256;
    float* ce2 = (float*)(ws + off); off += 256;
    float* cu1 = (float*)(ws + off); off += 256;
    float* cu2 = (float*)(ws + off); off += 256;

    hipMemsetAsync(s_acc, 0, S_BYTES + C_BYTES, stream);

    fold_kernel<<<1, 64, 0, stream>>>(
        (const float*)d_in[4],  (const float*)d_in[5],  (const float*)d_in[6],  (const float*)d_in[7],
        (const float*)d_in[8],  (const float*)d_in[9],
        (const float*)d_in[10], (const float*)d_in[11], (const float*)d_in[12], (const float*)d_in[13],
        (const float*)d_in[14], (const float*)d_in[15],
        (const float*)d_in[16], (const float*)d_in[17], (const float*)d_in[18], (const float*)d_in[19],
        (const float*)d_in[20], (const float*)d_in[21], (const float*)d_in[22], (const float*)d_in[23],
        (const float*)d_in[24], (const float*)d_in[25],
        (const float*)d_in[26], (const float*)d_in[27], (const float*)d_in[28], (const float*)d_in[29],
        (const float*)d_in[30], (const float*)d_in[31],
        mW1t, cm1, mW2t, cm2, eW1t, ce1, eW2t, ce2, uW1t, cu1, uW2t, cu2);

    edge_kernel<<<NE / 64, 256, 0, stream>>>(
        node_feats, edge_feats, src, dst,
        mW1t, cm1, mW2t, cm2, eW1t, ce1, eW2t, ce2, s_acc, cnt);

    node_kernel<<<(NN + 63) / 64, 256, 0, stream>>>(
        node_feats, s_acc, cnt, uW1t, cu1, uW2t, cu2, (float*)d_out);
}

// Round 3
// 547.444 us; speedup vs baseline: 1.4103x; 1.4103x over previous
//
#include <hip/hip_runtime.h>
#include <hip/hip_bf16.h>

#define NN 50000
#define NE 800000

typedef __bf16 bf16_t;
typedef bf16_t bf16x8 __attribute__((ext_vector_type(8)));
typedef float f32x4 __attribute__((ext_vector_type(4)));

// fast exact-enough gelu: x * sigmoid(1.595769x + 0.0713548x^3)
// (tanh-form gelu rewritten as sigmoid; max abs err vs erf-gelu ~4e-4)
__device__ __forceinline__ float gelu_f(float x) {
    float v = x * fmaf(x * x, 0.07135481627f, 1.595769122f);
    float e = __expf(-v);
    return x * __builtin_amdgcn_rcpf(1.0f + e);
}

// ---------------- weight folding into MFMA B-fragment order ----------------
// B-fragment layout for 16x16x32: lane L=(quad*16+lrow) holds B[k=quad*8+j][col]
// with col = nt*16+lrow. Linear: idx = ((nt*nkc + (k>>5))*64 + ((k>>3)&3)*16 + lrow)*8 + (k&7)
__device__ void fold_frag(int K, const float* W, const float* g, const float* b,
                          const float* mu, const float* v, const float* c,
                          bf16_t* Wf, float* cb, int n) {
    float acc = c[n];
    const int nt = n >> 4, lrow = n & 15, nkc = K >> 5;
    for (int k = 0; k < K; ++k) {
        float w = W[k * 64 + n];
        float s = 1.0f, o = 0.0f;
        if (g) {
            s = g[k] * __frsqrt_rn(v[k] + 1e-3f);
            o = b[k] - mu[k] * s;
        }
        int idx = ((nt * nkc + (k >> 5)) * 64 + ((k >> 3) & 3) * 16 + lrow) * 8 + (k & 7);
        Wf[idx] = (bf16_t)(w * s);
        acc += o * w;
    }
    cb[n] = acc;
}

__global__ void fold_kernel(
    const float* mg1, const float* mb1, const float* mmu1, const float* mv1,
    const float* mW1, const float* mc1,
    const float* mg2, const float* mb2, const float* mmu2, const float* mv2,
    const float* mW2, const float* mc2,
    const float* eW1, const float* ec1, const float* eW2, const float* ec2,
    const float* ug1, const float* ub1, const float* umu1, const float* uv1,
    const float* uW1, const float* uc1,
    const float* ug2, const float* ub2, const float* umu2, const float* uv2,
    const float* uW2, const float* uc2,
    bf16_t* wcat,            // [4][4096] mW1f,mW2f,eW1f,eW2f
    bf16_t* uW1f, bf16_t* uW2f,
    float* cm1, float* cm2, float* ce1, float* ce2, float* cu1, float* cu2)
{
    int n = threadIdx.x;
    if (n >= 64) return;
    switch (blockIdx.x) {
        case 0: fold_frag(64,  mW1, mg1, mb1, mmu1, mv1, mc1, wcat,         cm1, n); break;
        case 1: fold_frag(64,  mW2, mg2, mb2, mmu2, mv2, mc2, wcat + 4096,  cm2, n); break;
        case 2: fold_frag(64,  eW1, nullptr, nullptr, nullptr, nullptr, ec1, wcat + 8192,  ce1, n); break;
        case 3: fold_frag(64,  eW2, nullptr, nullptr, nullptr, nullptr, ec2, wcat + 12288, ce2, n); break;
        case 4: fold_frag(128, uW1, ug1, ub1, umu1, uv1, uc1, uW1f, cu1, n); break;
        case 5: fold_frag(64,  uW2, ug2, ub2, umu2, uv2, uc2, uW2f, cu2, n); break;
    }
}

// ---------------- helpers ----------------
// fp32 row (64 floats) -> hi/lo bf16 fragments (error compensation for L1)
__device__ __forceinline__ void mk_frag_hilo(const float* row, int quad,
        bf16x8& hi0, bf16x8& lo0, bf16x8& hi1, bf16x8& lo1)
{
    #pragma unroll
    for (int j = 0; j < 8; ++j) {
        float x0 = row[quad * 8 + j];
        float x1 = row[32 + quad * 8 + j];
        bf16_t h0 = (bf16_t)x0, h1 = (bf16_t)x1;
        hi0[j] = h0; lo0[j] = (bf16_t)(x0 - (float)h0);
        hi1[j] = h1; lo1[j] = (bf16_t)(x1 - (float)h1);
    }
}

// B-fragment load: conflict-free, contiguous per wave (lane*16B)
__device__ __forceinline__ bf16x8 ldb(const bf16_t* wf, int slot, int lane) {
    return *(const bf16x8*)(wf + (slot * 64 + lane) * 8);
}

__device__ __forceinline__ void gemm64_hilo(const bf16_t* wf, int m,
        bf16x8 h0, bf16x8 l0, bf16x8 h1, bf16x8 l1, f32x4 (&acc)[4], int lane)
{
    #pragma unroll
    for (int nt = 0; nt < 4; ++nt) {
        bf16x8 b0 = ldb(wf, m * 8 + nt * 2 + 0, lane);
        bf16x8 b1 = ldb(wf, m * 8 + nt * 2 + 1, lane);
        f32x4 c = {0.f, 0.f, 0.f, 0.f};
        c = __builtin_amdgcn_mfma_f32_16x16x32_bf16(h0, b0, c, 0, 0, 0);
        c = __builtin_amdgcn_mfma_f32_16x16x32_bf16(l0, b0, c, 0, 0, 0);
        c = __builtin_amdgcn_mfma_f32_16x16x32_bf16(h1, b1, c, 0, 0, 0);
        c = __builtin_amdgcn_mfma_f32_16x16x32_bf16(l1, b1, c, 0, 0, 0);
        acc[nt] = c;
    }
}

__device__ __forceinline__ void gemm64(const bf16_t* wf, int m,
        bf16x8 a0, bf16x8 a1, f32x4 (&acc)[4], int lane)
{
    #pragma unroll
    for (int nt = 0; nt < 4; ++nt) {
        bf16x8 b0 = ldb(wf, m * 8 + nt * 2 + 0, lane);
        bf16x8 b1 = ldb(wf, m * 8 + nt * 2 + 1, lane);
        f32x4 c = {0.f, 0.f, 0.f, 0.f};
        c = __builtin_amdgcn_mfma_f32_16x16x32_bf16(a0, b0, c, 0, 0, 0);
        c = __builtin_amdgcn_mfma_f32_16x16x32_bf16(a1, b1, c, 0, 0, 0);
        acc[nt] = c;
    }
}

// epilogue: gelu -> per-wave A-fragment-order buffer (1024 bf16)
// element (m=quad*4+r, k=nt*16+lrow) -> line (k>>3)*16+m, byte k&7
__device__ __forceinline__ void epi_to_frag(const f32x4 (&acc)[4], const float* bias,
        bf16_t* h, int lrow, int quad)
{
    #pragma unroll
    for (int nt = 0; nt < 4; ++nt) {
        float bb = bias[nt * 16 + lrow];
        #pragma unroll
        for (int r = 0; r < 4; ++r)
            h[((nt * 2 + (lrow >> 3)) * 16 + quad * 4 + r) * 8 + (lrow & 7)] =
                (bf16_t)gelu_f(acc[nt][r] + bb);
    }
}

// ---------------- edge kernel: msg/er MLPs + gated scatter ----------------
__global__ __launch_bounds__(256) void edge_kernel(
    const float* __restrict__ node_feats, const float* __restrict__ edge_feats,
    const int* __restrict__ src, const int* __restrict__ dst,
    const bf16_t* __restrict__ wcat,
    const float* __restrict__ cm1, const float* __restrict__ cm2,
    const float* __restrict__ ce1, const float* __restrict__ ce2,
    float* __restrict__ s_acc, int* __restrict__ cnt)
{
    __shared__ bf16_t wf[16384];     // 32 KB: 4 matrices, fragment order
    __shared__ bf16_t hf[4][1024];   // 8 KB: per-wave L1->L2 round-trip (A-frag order)

    const int tid  = threadIdx.x;
    const int wave = tid >> 6;
    const int lane = tid & 63;
    const int quad = lane >> 4;
    const int lrow = lane & 15;

    #pragma unroll
    for (int i = 0; i < 8; ++i) {
        int chunk = tid + i * 256;   // 0..2047 x 16B
        *(bf16x8*)(wf + chunk * 8) = *(const bf16x8*)(wcat + chunk * 8);
    }
    __syncthreads();

    const int ebase = blockIdx.x * 64 + wave * 16;
    bf16_t* h = hf[wave];

    // per-edge count (exactly once: lanes 0..15 of each wave)
    if (quad == 0) atomicAdd(&cnt[src[ebase + lrow]], 1);

    f32x4 acc[4];

    // ---- edge-transformer path ----
    {
        const float* erow = edge_feats + (size_t)(ebase + lrow) * 64;
        bf16x8 h0, l0, h1, l1;
        mk_frag_hilo(erow, quad, h0, l0, h1, l1);
        gemm64_hilo(wf, 2, h0, l0, h1, l1, acc, lane);
        epi_to_frag(acc, ce1, h, lrow, quad);
    }
    float er[4][4];
    {
        bf16x8 a0 = *(const bf16x8*)(h + lane * 8);
        bf16x8 a1 = *(const bf16x8*)(h + (lane + 64) * 8);
        gemm64(wf, 3, a0, a1, acc, lane);
        #pragma unroll
        for (int nt = 0; nt < 4; ++nt) {
            float bb = ce2[nt * 16 + lrow];
            #pragma unroll
            for (int r = 0; r < 4; ++r) er[nt][r] = gelu_f(acc[nt][r] + bb);
        }
    }

    // ---- message path ----
    {
        const int dnode = dst[ebase + lrow];
        const float* nrow = node_feats + (size_t)dnode * 64;
        bf16x8 h0, l0, h1, l1;
        mk_frag_hilo(nrow, quad, h0, l0, h1, l1);
        gemm64_hilo(wf, 0, h0, l0, h1, l1, acc, lane);
        epi_to_frag(acc, cm1, h, lrow, quad);
    }
    float msg[4][4];
    {
        bf16x8 a0 = *(const bf16x8*)(h + lane * 8);
        bf16x8 a1 = *(const bf16x8*)(h + (lane + 64) * 8);
        gemm64(wf, 1, a0, a1, acc, lane);
        #pragma unroll
        for (int nt = 0; nt < 4; ++nt) {
            float bb = cm2[nt * 16 + lrow];
            #pragma unroll
            for (int r = 0; r < 4; ++r) msg[nt][r] = gelu_f(acc[nt][r] + bb);
        }
    }

    // ---- gate + scatter (C layout: row=quad*4+r, col=nt*16+lrow) ----
    #pragma unroll
    for (int r = 0; r < 4; ++r) {
        float* srow = s_acc + (size_t)src[ebase + quad * 4 + r] * 64;
        #pragma unroll
        for (int nt = 0; nt < 4; ++nt)
            unsafeAtomicAdd(srow + nt * 16 + lrow, msg[nt][r] * er[nt][r]);
    }
}

// ---------------- node kernel: concat + update MLP ----------------
__global__ __launch_bounds__(256) void node_kernel(
    const float* __restrict__ node_feats,
    const float* __restrict__ s_acc, const int* __restrict__ cnt,
    const bf16_t* __restrict__ uW1f, const float* __restrict__ cu1,
    const bf16_t* __restrict__ uW2f, const float* __restrict__ cu2,
    float* __restrict__ out)
{
    __shared__ bf16_t w1f[8192];     // 16 KB, K=128 fragment order
    __shared__ bf16_t w2f[4096];     // 8 KB
    __shared__ bf16_t hf[4][1024];

    const int tid  = threadIdx.x;
    const int wave = tid >> 6;
    const int lane = tid & 63;
    const int quad = lane >> 4;
    const int lrow = lane & 15;

    #pragma unroll
    for (int i = 0; i < 4; ++i) {
        int chunk = tid + i * 256;
        *(bf16x8*)(w1f + chunk * 8) = *(const bf16x8*)(uW1f + chunk * 8);
    }
    #pragma unroll
    for (int i = 0; i < 2; ++i) {
        int chunk = tid + i * 256;
        *(bf16x8*)(w2f + chunk * 8) = *(const bf16x8*)(uW2f + chunk * 8);
    }
    __syncthreads();

    const int nbase = blockIdx.x * 64 + wave * 16;
    int arow = nbase + lrow;
    arow = arow < NN ? arow : NN - 1;   // clamp gather; stores predicated below

    const float* nf   = node_feats + (size_t)arow * 64;
    const float* srow = s_acc + (size_t)arow * 64;
    float inv = 1.0f / fmaxf((float)cnt[arow], 1.0f);

    bf16x8 ah[4], al[4];
    #pragma unroll
    for (int j = 0; j < 8; ++j) {
        float x0 = nf[quad * 8 + j];
        float x1 = nf[32 + quad * 8 + j];
        float x2 = srow[quad * 8 + j] * inv;
        float x3 = srow[32 + quad * 8 + j] * inv;
        bf16_t h0 = (bf16_t)x0, h1 = (bf16_t)x1, h2 = (bf16_t)x2, h3 = (bf16_t)x3;
        ah[0][j] = h0; al[0][j] = (bf16_t)(x0 - (float)h0);
        ah[1][j] = h1; al[1][j] = (bf16_t)(x1 - (float)h1);
        ah[2][j] = h2; al[2][j] = (bf16_t)(x2 - (float)h2);
        ah[3][j] = h3; al[3][j] = (bf16_t)(x3 - (float)h3);
    }

    f32x4 acc[4];
    #pragma unroll
    for (int nt = 0; nt < 4; ++nt) {
        f32x4 c = {0.f, 0.f, 0.f, 0.f};
        #pragma unroll
        for (int kk = 0; kk < 4; ++kk) {
            bf16x8 b = *(const bf16x8*)(w1f + ((nt * 4 + kk) * 64 + lane) * 8);
            c = __builtin_amdgcn_mfma_f32_16x16x32_bf16(ah[kk], b, c, 0, 0, 0);
            c = __builtin_amdgcn_mfma_f32_16x16x32_bf16(al[kk], b, c, 0, 0, 0);
        }
        acc[nt] = c;
    }
    bf16_t* hb = hf[wave];
    epi_to_frag(acc, cu1, hb, lrow, quad);

    bf16x8 ha0 = *(const bf16x8*)(hb + lane * 8);
    bf16x8 ha1 = *(const bf16x8*)(hb + (lane + 64) * 8);
    gemm64(w2f, 0, ha0, ha1, acc, lane);

    #pragma unroll
    for (int nt = 0; nt < 4; ++nt) {
        int col = nt * 16 + lrow;
        float bb = cu2[col];
        #pragma unroll
        for (int r = 0; r < 4; ++r) {
            int row = nbase + quad * 4 + r;
            if (row < NN)
                out[(size_t)row * 64 + col] = gelu_f(acc[nt][r] + bb);
        }
    }
}

// ---------------- launch ----------------
extern "C" void kernel_launch(void* const* d_in, const int* in_sizes, int n_in,
                              void* d_out, int out_size, void* d_ws, size_t ws_size,
                              hipStream_t stream) {
    const float* node_feats = (const float*)d_in[0];
    const float* edge_feats = (const float*)d_in[1];
    const int*   src        = (const int*)d_in[2];
    const int*   dst        = (const int*)d_in[3];

    char* ws = (char*)d_ws;
    const size_t S_BYTES = (size_t)NN * 64 * 4;       // 12,800,000
    const size_t C_BYTES = (size_t)NN * 4;            //    200,000
    float* s_acc = (float*)ws;
    int*   cnt   = (int*)(ws + S_BYTES);
    size_t off = S_BYTES + C_BYTES;
    bf16_t* wcat = (bf16_t*)(ws + off); off += 32768;   // mW1f,mW2f,eW1f,eW2f
    bf16_t* uW1f = (bf16_t*)(ws + off); off += 16384;
    bf16_t* uW2f = (bf16_t*)(ws + off); off += 8192;
    float* cm1 = (float*)(ws + off); off += 256;
    float* cm2 = (float*)(ws + off); off += 256;
    float* ce1 = (float*)(ws + off); off += 256;
    float* ce2 = (float*)(ws + off); off += 256;
    float* cu1 = (float*)(ws + off); off += 256;
    float* cu2 = (float*)(ws + off); off += 256;

    hipMemsetAsync(s_acc, 0, S_BYTES + C_BYTES, stream);

    fold_kernel<<<6, 64, 0, stream>>>(
        (const float*)d_in[4],  (const float*)d_in[5],  (const float*)d_in[6],  (const float*)d_in[7],
        (const float*)d_in[8],  (const float*)d_in[9],
        (const float*)d_in[10], (const float*)d_in[11], (const float*)d_in[12], (const float*)d_in[13],
        (const float*)d_in[14], (const float*)d_in[15],
        (const float*)d_in[16], (const float*)d_in[17], (const float*)d_in[18], (const float*)d_in[19],
        (const float*)d_in[20], (const float*)d_in[21], (const float*)d_in[22], (const float*)d_in[23],
        (const float*)d_in[24], (const float*)d_in[25],
        (const float*)d_in[26], (const float*)d_in[27], (const float*)d_in[28], (const float*)d_in[29],
        (const float*)d_in[30], (const float*)d_in[31],
        wcat, uW1f, uW2f, cm1, cm2, ce1, ce2, cu1, cu2);

    edge_kernel<<<NE / 64, 256, 0, stream>>>(
        node_feats, edge_feats, src, dst,
        wcat, cm1, cm2, ce1, ce2, s_acc, cnt);

    node_kernel<<<(NN + 63) / 64, 256, 0, stream>>>(
        node_feats, s_acc, cnt, uW1f, cu1, uW2f, cu2, (float*)d_out);
}